// Round 5
// baseline (214.002 us; speedup 1.0000x reference)
//
#include <hip/hip_runtime.h>
#include <hip/hip_bf16.h>
#include <hip/hip_fp16.h>

// DistanceEncoder: B=2, N=512, HID=OUT=128. All-pairs distances -> 3 SiLU-MLP
// layers -> mean over j -> projection.
// R5 = R4 with the LDS pointer-array static-initializer compile error fixed
// (ternary ping-pong instead of ushort* T[2] = {sA,sB}).
// Operand-swapped MFMA (A = W^T VGPR-resident, B = activations from LDS).
// D rows = output channels -> contiguous b64 LDS stores; reads stay b128.

typedef _Float16 half8 __attribute__((ext_vector_type(8)));
typedef _Float16 half4 __attribute__((ext_vector_type(4)));
typedef __attribute__((ext_vector_type(4))) float floatx4;

#define LDP 136   // ushorts; row stride 272 B

// ws byte offsets
#define WS_FLAG   0          // int: 1 = fp32 inputs, 0 = bf16
#define WS_WT2    16         // f16 frags: [L(5)][w(4)][mt(2)][kk(4)][lane(64)][8] = 163840 B
#define WS_WOT    163856     // Wo^T fp32 [o(128)][k(128)] = 65536 B
#define WS_PARAMS 229392     // 8 x 128 fp32: w10,b10,b20,b11,b21,b12,b22,bo
#define WS_XF     233488     // x fp32, 2048 floats
#define WS_NEED   241680

__device__ __forceinline__ float bf2f(ushort u) {
  union { unsigned int i; float f; } v; v.i = ((unsigned int)u) << 16; return v.f;
}
__device__ __forceinline__ ushort f2bf(float f) {
  union { float f; unsigned int i; } v; v.f = f;
  return (ushort)((v.i + 0x7FFFu + ((v.i >> 16) & 1u)) >> 16);
}
__device__ __forceinline__ float silu_f(float a) {
  float e = __builtin_amdgcn_exp2f(-1.44269504089f * a);   // exp(-a)
  return a * __builtin_amdgcn_rcpf(1.0f + e);
}
__device__ __forceinline__ float dload(const void* p, int idx, int isf32) {
  return isf32 ? ((const float*)p)[idx] : bf2f(((const ushort*)p)[idx]);
}

// per-block dtype sniff: fp32 read as ushorts -> ~half of low-half words have
// insane bf16 exponents; true bf16 N(0,1) -> none.
__device__ __forceinline__ int sniff_block(const ushort* __restrict__ x,
                                           int* scnt, int tid, int nthreads) {
  if (tid == 0) *scnt = 0;
  __syncthreads();
  int c = 0;
  for (int i = tid; i < 256; i += nthreads) {
    const int e = (x[i] >> 7) & 0xFF;
    if (e >= 0xC0 || (e >= 1 && e <= 0x40)) ++c;
  }
  if (c) atomicAdd(scnt, c);
  __syncthreads();
  return (*scnt > 8) ? 1 : 0;
}

// ---- kernel 1: build ws image ---------------------------------------------
// Weight fragment packing: element (L,w,mt,kk,lane,t) = f16(W_L[k][c']),
// k = kk*32+(lane>>4)*8+t, c' = w*32+mt*16+(lane&15). Swapped-form A-operand.
__global__ __launch_bounds__(256) void prep_kernel(
    const void* __restrict__ x,
    const void* __restrict__ w10, const void* __restrict__ b10,
    const void* __restrict__ W20, const void* __restrict__ b20,
    const void* __restrict__ W11, const void* __restrict__ b11,
    const void* __restrict__ W21, const void* __restrict__ b21,
    const void* __restrict__ W12, const void* __restrict__ b12,
    const void* __restrict__ W22, const void* __restrict__ b22,
    const void* __restrict__ Wo,  const void* __restrict__ bo,
    char* __restrict__ ws)
{
  __shared__ int scnt;
  const int tid = threadIdx.x;
  const int isf32 = sniff_block((const ushort*)x, &scnt, tid, 256);
  const int blk = blockIdx.x;
  ushort* wt2    = (ushort*)(ws + WS_WT2);
  float*  wot    = (float*)(ws + WS_WOT);
  float*  params = (float*)(ws + WS_PARAMS);
  float*  xf     = (float*)(ws + WS_XF);

  if (blk < 20) {                       // weight fragments
    const int L = blk >> 2, w = blk & 3;
    const void* src = (L == 0) ? W20 : (L == 1) ? W11 : (L == 2) ? W21
                    : (L == 3) ? W12 : W22;
#pragma unroll
    for (int uu = 0; uu < 2; ++uu) {
      const int u = tid + uu * 256;     // 512 units: (mt,kk,lane)
      const int mt = u >> 8, kk = (u >> 6) & 3, lane = u & 63;
      const int ln = lane & 15, quad = lane >> 4;
      const int cp = w * 32 + mt * 16 + ln;
      ushort* dst = wt2 + ((((L * 4 + w) * 2 + mt) * 4 + kk) * 64 + lane) * 8;
      for (int t = 0; t < 8; ++t) {
        const int k = kk * 32 + quad * 8 + t;
        union { _Float16 h; ushort us; } cv;
        cv.h = (_Float16)dload(src, k * 128 + cp, isf32);
        dst[t] = cv.us;
      }
    }
  } else if (blk == 20) {               // Wo^T fp32
    for (int idx = tid; idx < 16384; idx += 256) {
      const int o = idx >> 7, k = idx & 127;
      wot[o * 128 + k] = dload(Wo, k * 128 + o, isf32);
    }
  } else {                              // params + x + flag
    if (tid < 128) {
      const void* vecs[8] = {w10, b10, b20, b11, b21, b12, b22, bo};
      for (int v = 0; v < 8; ++v) params[v * 128 + tid] = dload(vecs[v], tid, isf32);
    }
    for (int i = tid; i < 2048; i += 256) xf[i] = dload(x, i, isf32);
    if (tid == 0) *(int*)(ws + WS_FLAG) = isf32;
  }
}

// ---- swapped-form GEMM layer ----------------------------------------------
// D[c'][j] = sum_c W[c][c'] * act[j][c]; A = W^T (regs), B = act (LDS b128).
// C/D: lane l reg r -> c' = w*32+mt*16+quad*4+r, j = nt*16+ln -> b64 store.
template<int ACT>
__device__ __forceinline__ void layerS(
    const ushort* sIn, ushort* sOut, const half8 (&aw)[2][4],
    const floatx4 (&bb)[2], int ln, int quad, int w)
{
#pragma unroll
  for (int nt = 0; nt < 8; ++nt) {
    half8 bF[4];
    const ushort* rp = sIn + (nt * 16 + ln) * LDP + quad * 8;
#pragma unroll
    for (int kk = 0; kk < 4; ++kk)
      bF[kk] = *(const half8*)(const void*)(rp + kk * 32);
#pragma unroll
    for (int mt = 0; mt < 2; ++mt) {
      floatx4 acc = bb[mt];   // bias pre-loaded into accumulator
#pragma unroll
      for (int kk = 0; kk < 4; ++kk)
        acc = __builtin_amdgcn_mfma_f32_16x16x32_f16(aw[mt][kk], bF[kk], acc, 0, 0, 0);
      half4 hv;
#pragma unroll
      for (int r = 0; r < 4; ++r) {
        float v = acc[r];
        if (ACT) v = silu_f(v);
        hv[r] = (_Float16)v;
      }
      *(half4*)(void*)(sOut + (nt * 16 + ln) * LDP + w * 32 + mt * 16 + quad * 4) = hv;
    }
  }
}

// last layer (W22): accumulate per-lane partial column sums, no store
__device__ __forceinline__ void layerR(
    const ushort* sIn, const half8 (&aw)[2][4], floatx4 (&psum)[2],
    int ln, int quad)
{
#pragma unroll
  for (int nt = 0; nt < 8; ++nt) {
    half8 bF[4];
    const ushort* rp = sIn + (nt * 16 + ln) * LDP + quad * 8;
#pragma unroll
    for (int kk = 0; kk < 4; ++kk)
      bF[kk] = *(const half8*)(const void*)(rp + kk * 32);
#pragma unroll
    for (int mt = 0; mt < 2; ++mt) {
      floatx4 acc = {0.f, 0.f, 0.f, 0.f};
#pragma unroll
      for (int kk = 0; kk < 4; ++kk)
        acc = __builtin_amdgcn_mfma_f32_16x16x32_f16(aw[mt][kk], bF[kk], acc, 0, 0, 0);
      psum[mt] += acc;
    }
  }
}

// layer 0: a0[j][c] = silu(d_j*w10[c]+b10[c]); thread = (row=tid>>1, 64-col half)
__device__ __forceinline__ void layer0_store(
    ushort* dstT, const float* __restrict__ xf, const float* sw10,
    const float* sb10, float xi0, float xi1, int bbase, int chunk, int tid)
{
  const int row = tid >> 1, c0 = (tid & 1) * 64;
  const int j = chunk * 128 + row;
  const float dx = xi0 - xf[(bbase + j) * 2 + 0];
  const float dy = xi1 - xf[(bbase + j) * 2 + 1];
  const float d = sqrtf(dx * dx + dy * dy);
  ushort* dst = dstT + row * LDP + c0;
#pragma unroll
  for (int c = 0; c < 64; c += 4) {
    const floatx4 w4 = *(const floatx4*)(const void*)(sw10 + c0 + c);
    const floatx4 b4 = *(const floatx4*)(const void*)(sb10 + c0 + c);
    half4 hv;
#pragma unroll
    for (int q = 0; q < 4; ++q)
      hv[q] = (_Float16)silu_f(d * w4[q] + b4[q]);
    *(half4*)(void*)(dst + c) = hv;
  }
}

// ---- kernel 2: fused encoder ----------------------------------------------
__global__ __launch_bounds__(256, 2) void fused3(
    const char* __restrict__ ws, void* __restrict__ out)
{
  __shared__ __align__(16) ushort sA[128 * LDP];
  __shared__ __align__(16) ushort sB[128 * LDP];
  __shared__ __align__(16) float sw10[128];
  __shared__ __align__(16) float sb10[128];
  __shared__ __align__(16) float colsum[128];

  const int tid  = threadIdx.x;
  const int w    = tid >> 6;       // wave 0..3 owns channels 32w..32w+31
  const int lane = tid & 63;
  const int ln   = lane & 15;
  const int quad = lane >> 4;

  const int b = blockIdx.x >> 9;
  const int i = blockIdx.x & 511;
  const int bbase = b * 512;

  const int isf32      = *(const int*)(ws + WS_FLAG);
  const ushort* wt2    = (const ushort*)(ws + WS_WT2);
  const float*  wot    = (const float*)(ws + WS_WOT);
  const float*  params = (const float*)(ws + WS_PARAMS);
  const float*  xf     = (const float*)(ws + WS_XF);

  // W^T fragments -> registers (coalesced 16B/lane, once per block)
  half8 aw[5][2][4];
#pragma unroll
  for (int L = 0; L < 5; ++L)
#pragma unroll
    for (int mt = 0; mt < 2; ++mt)
#pragma unroll
      for (int kk = 0; kk < 4; ++kk)
        aw[L][mt][kk] = *(const half8*)(const void*)
            (wt2 + ((((L * 4 + w) * 2 + mt) * 4 + kk) * 64 + lane) * 8);

  // bias vectors for acc-init: bb[L][mt][r] = b_L[w*32+mt*16+quad*4+r]
  floatx4 bb[4][2];
#pragma unroll
  for (int L = 0; L < 4; ++L)
#pragma unroll
    for (int mt = 0; mt < 2; ++mt)
      bb[L][mt] = *(const floatx4*)(const void*)
          (params + (2 + L) * 128 + w * 32 + mt * 16 + quad * 4);

  if (tid < 128) {
    sw10[tid] = params[0 * 128 + tid];
    sb10[tid] = params[1 * 128 + tid];
  }
  const float xi0 = xf[(bbase + i) * 2 + 0];
  const float xi1 = xf[(bbase + i) * 2 + 1];
  __syncthreads();

  floatx4 psum[2] = {{0.f,0.f,0.f,0.f},{0.f,0.f,0.f,0.f}};

  layer0_store(sA, xf, sw10, sb10, xi0, xi1, bbase, 0, tid);

  for (int chunk = 0; chunk < 4; ++chunk) {
    ushort* Ta = (chunk & 1) ? sB : sA;   // a0 tile for this chunk
    ushort* Tb = (chunk & 1) ? sA : sB;
    __syncthreads();                                    // a0 ready
    layerS<0>(Ta, Tb, aw[0], bb[0], ln, quad, w);       // t0 = a0@W20+b20
    __syncthreads();
    layerS<1>(Tb, Ta, aw[1], bb[1], ln, quad, w);       // a1 = silu(t0@W11+b11)
    __syncthreads();
    layerS<0>(Ta, Tb, aw[2], bb[2], ln, quad, w);       // t1 = a1@W21+b21
    __syncthreads();
    layerS<1>(Tb, Ta, aw[3], bb[3], ln, quad, w);       // a2 = silu(t1@W12+b12)
    __syncthreads();
    layerR(Ta, aw[4], psum, ln, quad);                  // colsum partials (W22)
    if (chunk < 3)                                      // overlap next layer-0
      layer0_store(Tb, xf, sw10, sb10, xi0, xi1, bbase, chunk + 1, tid);
  }

  // reduce psum across the 16 ln-lanes of each quad-group; c' disjoint/wave
#pragma unroll
  for (int mt = 0; mt < 2; ++mt)
#pragma unroll
    for (int r = 0; r < 4; ++r) {
      float v = psum[mt][r];
      v += __shfl_xor(v, 1); v += __shfl_xor(v, 2);
      v += __shfl_xor(v, 4); v += __shfl_xor(v, 8);
      if (ln == 0) colsum[w * 32 + mt * 16 + quad * 4 + r] = v;
    }
  __syncthreads();

  if (tid < 128)   // mean + b22 (in place; reads happen after next barrier)
    colsum[tid] = colsum[tid] * (1.0f / 512.0f) + params[6 * 128 + tid];
  __syncthreads();

  // out[b,i,o] = mean . Wo[:,o] + bo[o]
  if (tid < 128) {
    const int o = tid;
    float s = params[7 * 128 + o];
    const floatx4* wrow = (const floatx4*)(const void*)(wot + o * 128);
#pragma unroll 4
    for (int k4 = 0; k4 < 32; ++k4) {
      const floatx4 wv = wrow[k4];
      const floatx4 cv = *(const floatx4*)(const void*)(colsum + k4 * 4);
      s += cv[0] * wv[0] + cv[1] * wv[1] + cv[2] * wv[2] + cv[3] * wv[3];
    }
    const int idx = (bbase + i) * 128 + o;
    if (isf32) ((float*)out)[idx] = s;
    else       ((ushort*)out)[idx] = f2bf(s);
  }
}

// ---- fallback (ws too small): fp32-direct, gathered bf16 weights ----------
template<bool ACT>
__device__ __forceinline__ void gemm_tile_g(
    const ushort* sIn, ushort* sOut, const float* __restrict__ W,
    const float* bias, int wave, int ln, int quad)
{
  typedef __attribute__((ext_vector_type(8))) short short8;
  const int row0 = wave * 32;
  short8 aF[2][4];
#pragma unroll
  for (int mt = 0; mt < 2; ++mt)
#pragma unroll
    for (int kk = 0; kk < 4; ++kk)
      aF[mt][kk] = *(const short8*)(const void*)(sIn + (row0 + mt * 16 + ln) * LDP + kk * 32 + quad * 8);
#pragma unroll
  for (int nt = 0; nt < 8; ++nt) {
    const int col = nt * 16 + ln;
    floatx4 acc0 = {0.f, 0.f, 0.f, 0.f};
    floatx4 acc1 = {0.f, 0.f, 0.f, 0.f};
#pragma unroll
    for (int kk = 0; kk < 4; ++kk) {
      short8 bF;
#pragma unroll
      for (int t = 0; t < 8; ++t)
        bF[t] = (short)f2bf(W[(kk * 32 + quad * 8 + t) * 128 + col]);
      acc0 = __builtin_amdgcn_mfma_f32_16x16x32_bf16(aF[0][kk], bF, acc0, 0, 0, 0);
      acc1 = __builtin_amdgcn_mfma_f32_16x16x32_bf16(aF[1][kk], bF, acc1, 0, 0, 0);
    }
    const float bv = bias[col];
#pragma unroll
    for (int r = 0; r < 4; ++r) {
      float v0 = acc0[r] + bv;
      float v1 = acc1[r] + bv;
      if (ACT) { v0 = silu_f(v0); v1 = silu_f(v1); }
      sOut[(row0 + quad * 4 + r) * LDP + col] = f2bf(v0);
      sOut[(row0 + 16 + quad * 4 + r) * LDP + col] = f2bf(v1);
    }
  }
}

__global__ __launch_bounds__(256, 2) void fused_direct(
    const float* __restrict__ x,
    const float* __restrict__ w10, const float* __restrict__ b10,
    const float* __restrict__ W20, const float* __restrict__ b20,
    const float* __restrict__ W11, const float* __restrict__ b11,
    const float* __restrict__ W21, const float* __restrict__ b21,
    const float* __restrict__ W12, const float* __restrict__ b12,
    const float* __restrict__ W22, const float* __restrict__ b22,
    const float* __restrict__ Wo,  const float* __restrict__ bo,
    float* __restrict__ out)
{
  __shared__ __align__(16) ushort sA[128 * LDP];
  __shared__ __align__(16) ushort sB[128 * LDP];
  __shared__ float sw10[128], sb10[128];
  __shared__ float sbias[5][128];
  __shared__ float colsum[128];
  __shared__ float dists[128];

  const int tid  = threadIdx.x;
  const int wave = tid >> 6;
  const int ln   = tid & 15;
  const int quad = (tid & 63) >> 4;
  const int b = blockIdx.x >> 9;
  const int i = blockIdx.x & 511;

  if (tid < 128) {
    sw10[tid] = w10[tid]; sb10[tid] = b10[tid];
    sbias[0][tid] = b20[tid]; sbias[1][tid] = b11[tid];
    sbias[2][tid] = b21[tid]; sbias[3][tid] = b12[tid];
    sbias[4][tid] = b22[tid]; colsum[tid] = 0.f;
  }
  const float xi0 = x[(b * 512 + i) * 2 + 0];
  const float xi1 = x[(b * 512 + i) * 2 + 1];
  __syncthreads();

  for (int chunk = 0; chunk < 4; ++chunk) {
    if (tid < 128) {
      const int j = chunk * 128 + tid;
      const float dx = xi0 - x[(b * 512 + j) * 2 + 0];
      const float dy = xi1 - x[(b * 512 + j) * 2 + 1];
      dists[tid] = sqrtf(dx * dx + dy * dy);
    }
    __syncthreads();
    for (int e = tid; e < 128 * 128; e += 256) {
      const int jj = e >> 7, c = e & 127;
      sA[jj * LDP + c] = f2bf(silu_f(dists[jj] * sw10[c] + sb10[c]));
    }
    __syncthreads();
    gemm_tile_g<false>(sA, sB, W20, sbias[0], wave, ln, quad);
    __syncthreads();
    gemm_tile_g<true >(sB, sA, W11, sbias[1], wave, ln, quad);
    __syncthreads();
    gemm_tile_g<false>(sA, sB, W21, sbias[2], wave, ln, quad);
    __syncthreads();
    gemm_tile_g<true >(sB, sA, W12, sbias[3], wave, ln, quad);
    __syncthreads();
    gemm_tile_g<false>(sB, sB, W22, sbias[4], wave, ln, quad);
    __syncthreads();
    if (tid < 128) {
      float s = 0.f;
      for (int jj = 0; jj < 128; ++jj) s += bf2f(sB[jj * LDP + tid]);
      atomicAdd(&colsum[tid], s);
    }
    __syncthreads();
  }

  if (tid < 128) {
    const int o = tid;
    float s = bo[o];
    for (int k = 0; k < 128; ++k) s += (colsum[k] * (1.0f / 512.0f)) * Wo[k * 128 + o];
    out[(b * 512 + i) * 128 + o] = s;
  }
}

extern "C" void kernel_launch(void* const* d_in, const int* in_sizes, int n_in,
                              void* d_out, int out_size, void* d_ws, size_t ws_size,
                              hipStream_t stream) {
  (void)in_sizes; (void)n_in; (void)out_size;
  if (ws_size >= (size_t)WS_NEED) {
    prep_kernel<<<22, 256, 0, stream>>>(
        d_in[0], d_in[1], d_in[2], d_in[3], d_in[4], d_in[5], d_in[6],
        d_in[7], d_in[8], d_in[9], d_in[10], d_in[11], d_in[12], d_in[13],
        d_in[14], (char*)d_ws);
    fused3<<<1024, 256, 0, stream>>>((const char*)d_ws, d_out);
  } else {
    fused_direct<<<1024, 256, 0, stream>>>(
        (const float*)d_in[0], (const float*)d_in[1], (const float*)d_in[2],
        (const float*)d_in[3], (const float*)d_in[4], (const float*)d_in[5],
        (const float*)d_in[6], (const float*)d_in[7], (const float*)d_in[8],
        (const float*)d_in[9], (const float*)d_in[10], (const float*)d_in[11],
        (const float*)d_in[12], (const float*)d_in[13], (const float*)d_in[14],
        (float*)d_out);
  }
}

// Round 6
// 207.788 us; speedup vs baseline: 1.0299x; 1.0299x over previous
//
#include <hip/hip_runtime.h>
#include <hip/hip_bf16.h>
#include <hip/hip_fp16.h>

// DistanceEncoder: B=2, N=512, HID=OUT=128. All-pairs distances -> 3 SiLU-MLP
// layers -> mean over j -> projection.
// R6: weights STREAMED per layer-pass (L2-hot, ping-pong 2x32 VGPR buffers;
// opaque index defeats LICM re-hoist -> no 160-reg liveness, no spills).
// j-chunk 64 -> tiles 2x17 KB, LDS ~36 KB -> 4 blocks/CU, launch_bounds(256,4).
// Operand-swapped MFMA: A = W^T (regs), B = activations (LDS b128 reads),
// C rows = channels -> contiguous b64 stores. fp32 accum, f16 activations.

typedef _Float16 half8 __attribute__((ext_vector_type(8)));
typedef _Float16 half4 __attribute__((ext_vector_type(4)));
typedef __attribute__((ext_vector_type(4))) float floatx4;

#define LDP 136      // ushorts; row stride 272 B (16B-aligned, balanced banks)
#define CJ  64       // j-rows per chunk
#define NCHUNK 8

// ws byte offsets
#define WS_FLAG   0          // int: 1 = fp32 inputs, 0 = bf16
#define WS_WT2    16         // f16 frags: [L(5)][w(4)][mt(2)][kk(4)][lane(64)][8] = 163840 B
#define WS_WOT    163856     // Wo^T fp32 [o(128)][k(128)] = 65536 B
#define WS_PARAMS 229392     // 8 x 128 fp32: w10,b10,b20,b11,b21,b12,b22,bo
#define WS_XF     233488     // x fp32, 2048 floats
#define WS_NEED   241680

__device__ __forceinline__ float bf2f(ushort u) {
  union { unsigned int i; float f; } v; v.i = ((unsigned int)u) << 16; return v.f;
}
__device__ __forceinline__ ushort f2bf(float f) {
  union { float f; unsigned int i; } v; v.f = f;
  return (ushort)((v.i + 0x7FFFu + ((v.i >> 16) & 1u)) >> 16);
}
__device__ __forceinline__ float silu_f(float a) {
  float e = __builtin_amdgcn_exp2f(-1.44269504089f * a);   // exp(-a)
  return a * __builtin_amdgcn_rcpf(1.0f + e);
}
__device__ __forceinline__ float dload(const void* p, int idx, int isf32) {
  return isf32 ? ((const float*)p)[idx] : bf2f(((const ushort*)p)[idx]);
}

// per-block dtype sniff: fp32 read as ushorts -> low halves have insane bf16
// exponents; true bf16 N(0,1) -> none.
__device__ __forceinline__ int sniff_block(const ushort* __restrict__ x,
                                           int* scnt, int tid, int nthreads) {
  if (tid == 0) *scnt = 0;
  __syncthreads();
  int c = 0;
  for (int i = tid; i < 256; i += nthreads) {
    const int e = (x[i] >> 7) & 0xFF;
    if (e >= 0xC0 || (e >= 1 && e <= 0x40)) ++c;
  }
  if (c) atomicAdd(scnt, c);
  __syncthreads();
  return (*scnt > 8) ? 1 : 0;
}

// ---- kernel 1: build ws image ---------------------------------------------
// Weight fragment packing: element (L,w,mt,kk,lane,t) = f16(W_L[k][c']),
// k = kk*32+(lane>>4)*8+t, c' = w*32+mt*16+(lane&15). Swapped-form A-operand.
__global__ __launch_bounds__(256) void prep_kernel(
    const void* __restrict__ x,
    const void* __restrict__ w10, const void* __restrict__ b10,
    const void* __restrict__ W20, const void* __restrict__ b20,
    const void* __restrict__ W11, const void* __restrict__ b11,
    const void* __restrict__ W21, const void* __restrict__ b21,
    const void* __restrict__ W12, const void* __restrict__ b12,
    const void* __restrict__ W22, const void* __restrict__ b22,
    const void* __restrict__ Wo,  const void* __restrict__ bo,
    char* __restrict__ ws)
{
  __shared__ int scnt;
  const int tid = threadIdx.x;
  const int isf32 = sniff_block((const ushort*)x, &scnt, tid, 256);
  const int blk = blockIdx.x;
  ushort* wt2    = (ushort*)(ws + WS_WT2);
  float*  wot    = (float*)(ws + WS_WOT);
  float*  params = (float*)(ws + WS_PARAMS);
  float*  xf     = (float*)(ws + WS_XF);

  if (blk < 20) {                       // weight fragments
    const int L = blk >> 2, w = blk & 3;
    const void* src = (L == 0) ? W20 : (L == 1) ? W11 : (L == 2) ? W21
                    : (L == 3) ? W12 : W22;
#pragma unroll
    for (int uu = 0; uu < 2; ++uu) {
      const int u = tid + uu * 256;     // 512 units: (mt,kk,lane)
      const int mt = u >> 8, kk = (u >> 6) & 3, lane = u & 63;
      const int ln = lane & 15, quad = lane >> 4;
      const int cp = w * 32 + mt * 16 + ln;
      ushort* dst = wt2 + ((((L * 4 + w) * 2 + mt) * 4 + kk) * 64 + lane) * 8;
      for (int t = 0; t < 8; ++t) {
        const int k = kk * 32 + quad * 8 + t;
        union { _Float16 h; ushort us; } cv;
        cv.h = (_Float16)dload(src, k * 128 + cp, isf32);
        dst[t] = cv.us;
      }
    }
  } else if (blk == 20) {               // Wo^T fp32
    for (int idx = tid; idx < 16384; idx += 256) {
      const int o = idx >> 7, k = idx & 127;
      wot[o * 128 + k] = dload(Wo, k * 128 + o, isf32);
    }
  } else {                              // params + x + flag
    if (tid < 128) {
      const void* vecs[8] = {w10, b10, b20, b11, b21, b12, b22, bo};
      for (int v = 0; v < 8; ++v) params[v * 128 + tid] = dload(vecs[v], tid, isf32);
    }
    for (int i = tid; i < 2048; i += 256) xf[i] = dload(x, i, isf32);
    if (tid == 0) *(int*)(ws + WS_FLAG) = isf32;
  }
}

// ---- streamed weight-fragment load (L2/L1-hot) ----------------------------
__device__ __forceinline__ void loadW(half8 (&aw)[2][4],
                                      const ushort* __restrict__ wt2o,
                                      int L, int w, int lane)
{
#pragma unroll
  for (int mt = 0; mt < 2; ++mt)
#pragma unroll
    for (int kk = 0; kk < 4; ++kk)
      aw[mt][kk] = *(const half8*)(const void*)
          (wt2o + ((((L * 4 + w) * 2 + mt) * 4 + kk) * 64 + lane) * 8);
}

// ---- swapped-form GEMM layer (CJ j-rows) ----------------------------------
// D[c'][j] = sum_c W[c][c'] * act[j][c]; A = W^T (regs), B = act (LDS b128).
// C/D: lane l reg r -> c' = w*32+mt*16+quad*4+r, j = nt*16+ln -> b64 store.
template<int ACT>
__device__ __forceinline__ void layerS(
    const ushort* sIn, ushort* sOut, const half8 (&aw)[2][4],
    const floatx4 (&bbL)[2], int ln, int quad, int w)
{
#pragma unroll
  for (int nt = 0; nt < CJ / 16; ++nt) {
    half8 bF[4];
    const ushort* rp = sIn + (nt * 16 + ln) * LDP + quad * 8;
#pragma unroll
    for (int kk = 0; kk < 4; ++kk)
      bF[kk] = *(const half8*)(const void*)(rp + kk * 32);
#pragma unroll
    for (int mt = 0; mt < 2; ++mt) {
      floatx4 acc = bbL[mt];   // bias pre-loaded into accumulator
#pragma unroll
      for (int kk = 0; kk < 4; ++kk)
        acc = __builtin_amdgcn_mfma_f32_16x16x32_f16(aw[mt][kk], bF[kk], acc, 0, 0, 0);
      half4 hv;
#pragma unroll
      for (int r = 0; r < 4; ++r) {
        float v = acc[r];
        if (ACT) v = silu_f(v);
        hv[r] = (_Float16)v;
      }
      *(half4*)(void*)(sOut + (nt * 16 + ln) * LDP + w * 32 + mt * 16 + quad * 4) = hv;
    }
  }
}

// last layer (W22): accumulate per-lane partial column sums, no store
__device__ __forceinline__ void layerR(
    const ushort* sIn, const half8 (&aw)[2][4], floatx4 (&psum)[2],
    int ln, int quad)
{
#pragma unroll
  for (int nt = 0; nt < CJ / 16; ++nt) {
    half8 bF[4];
    const ushort* rp = sIn + (nt * 16 + ln) * LDP + quad * 8;
#pragma unroll
    for (int kk = 0; kk < 4; ++kk)
      bF[kk] = *(const half8*)(const void*)(rp + kk * 32);
#pragma unroll
    for (int mt = 0; mt < 2; ++mt) {
      floatx4 acc = {0.f, 0.f, 0.f, 0.f};
#pragma unroll
      for (int kk = 0; kk < 4; ++kk)
        acc = __builtin_amdgcn_mfma_f32_16x16x32_f16(aw[mt][kk], bF[kk], acc, 0, 0, 0);
      psum[mt] += acc;
    }
  }
}

// layer 0: a0[j][c] = silu(d_j*w10[c]+b10[c]); thread -> row tid>>2, 32-col
// quarter (tid&3)*32. Each thread computes its own row distance (no LDS dists).
__device__ __forceinline__ void layer0_store(
    ushort* dstT, const float* __restrict__ xf, const float* sw10,
    const float* sb10, float xi0, float xi1, int bbase, int chunk, int tid)
{
  const int row = tid >> 2, c0 = (tid & 3) * 32;
  const int j = chunk * CJ + row;
  const float dx = xi0 - xf[(bbase + j) * 2 + 0];
  const float dy = xi1 - xf[(bbase + j) * 2 + 1];
  const float d = sqrtf(dx * dx + dy * dy);
  ushort* dst = dstT + row * LDP + c0;
#pragma unroll
  for (int c = 0; c < 32; c += 4) {
    const floatx4 w4 = *(const floatx4*)(const void*)(sw10 + c0 + c);
    const floatx4 b4 = *(const floatx4*)(const void*)(sb10 + c0 + c);
    half4 hv;
#pragma unroll
    for (int q = 0; q < 4; ++q)
      hv[q] = (_Float16)silu_f(d * w4[q] + b4[q]);
    *(half4*)(void*)(dst + c) = hv;
  }
}

// ---- kernel 2: fused encoder ----------------------------------------------
__global__ __launch_bounds__(256, 4) void fused4(
    const char* __restrict__ ws, void* __restrict__ out)
{
  __shared__ __align__(16) ushort sA[CJ * LDP];
  __shared__ __align__(16) ushort sB[CJ * LDP];
  __shared__ __align__(16) float sw10[128];
  __shared__ __align__(16) float sb10[128];
  __shared__ __align__(16) float colsum[128];

  const int tid  = threadIdx.x;
  const int w    = tid >> 6;       // wave 0..3 owns channels 32w..32w+31
  const int lane = tid & 63;
  const int ln   = lane & 15;
  const int quad = lane >> 4;

  const int b = blockIdx.x >> 9;
  const int i = blockIdx.x & 511;
  const int bbase = b * 512;

  const int isf32      = *(const int*)(ws + WS_FLAG);
  const ushort* wt2    = (const ushort*)(ws + WS_WT2);
  const float*  wot    = (const float*)(ws + WS_WOT);
  const float*  params = (const float*)(ws + WS_PARAMS);
  const float*  xf     = (const float*)(ws + WS_XF);

  // bias acc-init vectors: bb[L][mt][r] = b_L[w*32+mt*16+quad*4+r]
  floatx4 bb[4][2];
#pragma unroll
  for (int L = 0; L < 4; ++L)
#pragma unroll
    for (int mt = 0; mt < 2; ++mt)
      bb[L][mt] = *(const floatx4*)(const void*)
          (params + (2 + L) * 128 + w * 32 + mt * 16 + quad * 4);

  if (tid < 128) {
    sw10[tid] = params[0 * 128 + tid];
    sb10[tid] = params[1 * 128 + tid];
  }
  const float xi0 = xf[(bbase + i) * 2 + 0];
  const float xi1 = xf[(bbase + i) * 2 + 1];
  __syncthreads();   // sw10/sb10 ready

  floatx4 psum[2] = {{0.f,0.f,0.f,0.f},{0.f,0.f,0.f,0.f}};
  half8 awA[2][4], awB[2][4];

  layer0_store(sA, xf, sw10, sb10, xi0, xi1, bbase, 0, tid);

  for (int chunk = 0; chunk < NCHUNK; ++chunk) {
    // opaque zero: stops LICM from hoisting all 5 layers' weight loads out of
    // the chunk loop (which would recreate 160 live VGPRs -> spill).
    int zero = 0;
    asm volatile("" : "+v"(zero));
    const ushort* wt2o = wt2 + zero;

    ushort* Ta = (chunk & 1) ? sB : sA;   // a0 tile for this chunk
    ushort* Tb = (chunk & 1) ? sA : sB;

    loadW(awA, wt2o, 0, w, lane);
    __syncthreads();                                    // a0 ready
    loadW(awB, wt2o, 1, w, lane);                       // prefetch L1
    layerS<0>(Ta, Tb, awA, bb[0], ln, quad, w);         // t0 = a0@W20+b20
    __syncthreads();
    loadW(awA, wt2o, 2, w, lane);                       // prefetch L2
    layerS<1>(Tb, Ta, awB, bb[1], ln, quad, w);         // a1 = silu(t0@W11+b11)
    __syncthreads();
    loadW(awB, wt2o, 3, w, lane);                       // prefetch L3
    layerS<0>(Ta, Tb, awA, bb[2], ln, quad, w);         // t1 = a1@W21+b21
    __syncthreads();
    loadW(awA, wt2o, 4, w, lane);                       // prefetch L4
    layerS<1>(Tb, Ta, awB, bb[3], ln, quad, w);         // a2 = silu(t1@W12+b12)
    __syncthreads();
    layerR(Ta, awA, psum, ln, quad);                    // colsum partials (W22)
    if (chunk < NCHUNK - 1)                             // overlap next layer-0
      layer0_store(Tb, xf, sw10, sb10, xi0, xi1, bbase, chunk + 1, tid);
  }

  // reduce psum across the 16 ln-lanes of each quad-group; c' disjoint/wave
#pragma unroll
  for (int mt = 0; mt < 2; ++mt)
#pragma unroll
    for (int r = 0; r < 4; ++r) {
      float v = psum[mt][r];
      v += __shfl_xor(v, 1); v += __shfl_xor(v, 2);
      v += __shfl_xor(v, 4); v += __shfl_xor(v, 8);
      if (ln == 0) colsum[w * 32 + mt * 16 + quad * 4 + r] = v;
    }
  __syncthreads();

  if (tid < 128)   // mean + b22 (in place; reads happen after next barrier)
    colsum[tid] = colsum[tid] * (1.0f / 512.0f) + params[6 * 128 + tid];
  __syncthreads();

  // out[b,i,o] = mean . Wo[:,o] + bo[o]
  if (tid < 128) {
    const int o = tid;
    float s = params[7 * 128 + o];
    const floatx4* wrow = (const floatx4*)(const void*)(wot + o * 128);
#pragma unroll 4
    for (int k4 = 0; k4 < 32; ++k4) {
      const floatx4 wv = wrow[k4];
      const floatx4 cv = *(const floatx4*)(const void*)(colsum + k4 * 4);
      s += cv[0] * wv[0] + cv[1] * wv[1] + cv[2] * wv[2] + cv[3] * wv[3];
    }
    const int idx = (bbase + i) * 128 + o;
    if (isf32) ((float*)out)[idx] = s;
    else       ((ushort*)out)[idx] = f2bf(s);
  }
}

// ---- fallback (ws too small): fp32-direct, gathered bf16 weights ----------
template<bool ACT>
__device__ __forceinline__ void gemm_tile_g(
    const ushort* sIn, ushort* sOut, const float* __restrict__ W,
    const float* bias, int wave, int ln, int quad)
{
  typedef __attribute__((ext_vector_type(8))) short short8;
  const int row0 = wave * 32;
  short8 aF[2][4];
#pragma unroll
  for (int mt = 0; mt < 2; ++mt)
#pragma unroll
    for (int kk = 0; kk < 4; ++kk)
      aF[mt][kk] = *(const short8*)(const void*)(sIn + (row0 + mt * 16 + ln) * LDP + kk * 32 + quad * 8);
#pragma unroll
  for (int nt = 0; nt < 8; ++nt) {
    const int col = nt * 16 + ln;
    floatx4 acc0 = {0.f, 0.f, 0.f, 0.f};
    floatx4 acc1 = {0.f, 0.f, 0.f, 0.f};
#pragma unroll
    for (int kk = 0; kk < 4; ++kk) {
      short8 bF;
#pragma unroll
      for (int t = 0; t < 8; ++t)
        bF[t] = (short)f2bf(W[(kk * 32 + quad * 8 + t) * 128 + col]);
      acc0 = __builtin_amdgcn_mfma_f32_16x16x32_bf16(aF[0][kk], bF, acc0, 0, 0, 0);
      acc1 = __builtin_amdgcn_mfma_f32_16x16x32_bf16(aF[1][kk], bF, acc1, 0, 0, 0);
    }
    const float bv = bias[col];
#pragma unroll
    for (int r = 0; r < 4; ++r) {
      float v0 = acc0[r] + bv;
      float v1 = acc1[r] + bv;
      if (ACT) { v0 = silu_f(v0); v1 = silu_f(v1); }
      sOut[(row0 + quad * 4 + r) * LDP + col] = f2bf(v0);
      sOut[(row0 + 16 + quad * 4 + r) * LDP + col] = f2bf(v1);
    }
  }
}

__global__ __launch_bounds__(256, 2) void fused_direct(
    const float* __restrict__ x,
    const float* __restrict__ w10, const float* __restrict__ b10,
    const float* __restrict__ W20, const float* __restrict__ b20,
    const float* __restrict__ W11, const float* __restrict__ b11,
    const float* __restrict__ W21, const float* __restrict__ b21,
    const float* __restrict__ W12, const float* __restrict__ b12,
    const float* __restrict__ W22, const float* __restrict__ b22,
    const float* __restrict__ Wo,  const float* __restrict__ bo,
    float* __restrict__ out)
{
  __shared__ __align__(16) ushort sA[128 * LDP];
  __shared__ __align__(16) ushort sB[128 * LDP];
  __shared__ float sw10[128], sb10[128];
  __shared__ float sbias[5][128];
  __shared__ float colsum[128];
  __shared__ float dists[128];

  const int tid  = threadIdx.x;
  const int wave = tid >> 6;
  const int ln   = tid & 15;
  const int quad = (tid & 63) >> 4;
  const int b = blockIdx.x >> 9;
  const int i = blockIdx.x & 511;

  if (tid < 128) {
    sw10[tid] = w10[tid]; sb10[tid] = b10[tid];
    sbias[0][tid] = b20[tid]; sbias[1][tid] = b11[tid];
    sbias[2][tid] = b21[tid]; sbias[3][tid] = b12[tid];
    sbias[4][tid] = b22[tid]; colsum[tid] = 0.f;
  }
  const float xi0 = x[(b * 512 + i) * 2 + 0];
  const float xi1 = x[(b * 512 + i) * 2 + 1];
  __syncthreads();

  for (int chunk = 0; chunk < 4; ++chunk) {
    if (tid < 128) {
      const int j = chunk * 128 + tid;
      const float dx = xi0 - x[(b * 512 + j) * 2 + 0];
      const float dy = xi1 - x[(b * 512 + j) * 2 + 1];
      dists[tid] = sqrtf(dx * dx + dy * dy);
    }
    __syncthreads();
    for (int e = tid; e < 128 * 128; e += 256) {
      const int jj = e >> 7, c = e & 127;
      sA[jj * LDP + c] = f2bf(silu_f(dists[jj] * sw10[c] + sb10[c]));
    }
    __syncthreads();
    gemm_tile_g<false>(sA, sB, W20, sbias[0], wave, ln, quad);
    __syncthreads();
    gemm_tile_g<true >(sB, sA, W11, sbias[1], wave, ln, quad);
    __syncthreads();
    gemm_tile_g<false>(sA, sB, W21, sbias[2], wave, ln, quad);
    __syncthreads();
    gemm_tile_g<true >(sB, sA, W12, sbias[3], wave, ln, quad);
    __syncthreads();
    gemm_tile_g<false>(sB, sB, W22, sbias[4], wave, ln, quad);
    __syncthreads();
    if (tid < 128) {
      float s = 0.f;
      for (int jj = 0; jj < 128; ++jj) s += bf2f(sB[jj * LDP + tid]);
      atomicAdd(&colsum[tid], s);
    }
    __syncthreads();
  }

  if (tid < 128) {
    const int o = tid;
    float s = bo[o];
    for (int k = 0; k < 128; ++k) s += (colsum[k] * (1.0f / 512.0f)) * Wo[k * 128 + o];
    out[(b * 512 + i) * 128 + o] = s;
  }
}

extern "C" void kernel_launch(void* const* d_in, const int* in_sizes, int n_in,
                              void* d_out, int out_size, void* d_ws, size_t ws_size,
                              hipStream_t stream) {
  (void)in_sizes; (void)n_in; (void)out_size;
  if (ws_size >= (size_t)WS_NEED) {
    prep_kernel<<<22, 256, 0, stream>>>(
        d_in[0], d_in[1], d_in[2], d_in[3], d_in[4], d_in[5], d_in[6],
        d_in[7], d_in[8], d_in[9], d_in[10], d_in[11], d_in[12], d_in[13],
        d_in[14], (char*)d_ws);
    fused4<<<1024, 256, 0, stream>>>((const char*)d_ws, d_out);
  } else {
    fused_direct<<<1024, 256, 0, stream>>>(
        (const float*)d_in[0], (const float*)d_in[1], (const float*)d_in[2],
        (const float*)d_in[3], (const float*)d_in[4], (const float*)d_in[5],
        (const float*)d_in[6], (const float*)d_in[7], (const float*)d_in[8],
        (const float*)d_in[9], (const float*)d_in[10], (const float*)d_in[11],
        (const float*)d_in[12], (const float*)d_in[13], (const float*)d_in[14],
        (float*)d_out);
  }
}

// Round 7
// 205.253 us; speedup vs baseline: 1.0426x; 1.0124x over previous
//
#include <hip/hip_runtime.h>
#include <hip/hip_bf16.h>
#include <hip/hip_fp16.h>

// DistanceEncoder: B=2, N=512, HID=OUT=128. All-pairs distances -> 3 SiLU-MLP
// layers -> mean over j -> projection.
// R7: register diet vs R6 — SINGLE streamed weight buffer (32 VGPR, loaded
// per layer-pass, L1-hot) and biases moved to LDS (acc-init read per layer).
// Live set ~90 regs -> no spill at the launch_bounds(256,4) 128-VGPR cap.
// Operand-swapped MFMA: A = W^T (regs), B = activations (LDS b128 reads),
// C rows = channels -> contiguous b64 stores. fp32 accum, f16 activations.

typedef _Float16 half8 __attribute__((ext_vector_type(8)));
typedef _Float16 half4 __attribute__((ext_vector_type(4)));
typedef __attribute__((ext_vector_type(4))) float floatx4;

#define LDP 136      // ushorts; row stride 272 B (16B-aligned)
#define CJ  64       // j-rows per chunk
#define NCHUNK 8

// ws byte offsets
#define WS_FLAG   0          // int: 1 = fp32 inputs, 0 = bf16
#define WS_WT2    16         // f16 frags: [L(5)][w(4)][mt(2)][kk(4)][lane(64)][8] = 163840 B
#define WS_WOT    163856     // Wo^T fp32 [o(128)][k(128)] = 65536 B
#define WS_PARAMS 229392     // 8 x 128 fp32: w10,b10,b20,b11,b21,b12,b22,bo
#define WS_XF     233488     // x fp32, 2048 floats
#define WS_NEED   241680

__device__ __forceinline__ float bf2f(ushort u) {
  union { unsigned int i; float f; } v; v.i = ((unsigned int)u) << 16; return v.f;
}
__device__ __forceinline__ ushort f2bf(float f) {
  union { float f; unsigned int i; } v; v.f = f;
  return (ushort)((v.i + 0x7FFFu + ((v.i >> 16) & 1u)) >> 16);
}
__device__ __forceinline__ float silu_f(float a) {
  float e = __builtin_amdgcn_exp2f(-1.44269504089f * a);   // exp(-a)
  return a * __builtin_amdgcn_rcpf(1.0f + e);
}
__device__ __forceinline__ float dload(const void* p, int idx, int isf32) {
  return isf32 ? ((const float*)p)[idx] : bf2f(((const ushort*)p)[idx]);
}

// per-block dtype sniff: fp32 read as ushorts -> low halves have insane bf16
// exponents; true bf16 N(0,1) -> none.
__device__ __forceinline__ int sniff_block(const ushort* __restrict__ x,
                                           int* scnt, int tid, int nthreads) {
  if (tid == 0) *scnt = 0;
  __syncthreads();
  int c = 0;
  for (int i = tid; i < 256; i += nthreads) {
    const int e = (x[i] >> 7) & 0xFF;
    if (e >= 0xC0 || (e >= 1 && e <= 0x40)) ++c;
  }
  if (c) atomicAdd(scnt, c);
  __syncthreads();
  return (*scnt > 8) ? 1 : 0;
}

// ---- kernel 1: build ws image ---------------------------------------------
// Weight fragment packing: element (L,w,mt,kk,lane,t) = f16(W_L[k][c']),
// k = kk*32+(lane>>4)*8+t, c' = w*32+mt*16+(lane&15). Swapped-form A-operand.
__global__ __launch_bounds__(256) void prep_kernel(
    const void* __restrict__ x,
    const void* __restrict__ w10, const void* __restrict__ b10,
    const void* __restrict__ W20, const void* __restrict__ b20,
    const void* __restrict__ W11, const void* __restrict__ b11,
    const void* __restrict__ W21, const void* __restrict__ b21,
    const void* __restrict__ W12, const void* __restrict__ b12,
    const void* __restrict__ W22, const void* __restrict__ b22,
    const void* __restrict__ Wo,  const void* __restrict__ bo,
    char* __restrict__ ws)
{
  __shared__ int scnt;
  const int tid = threadIdx.x;
  const int isf32 = sniff_block((const ushort*)x, &scnt, tid, 256);
  const int blk = blockIdx.x;
  ushort* wt2    = (ushort*)(ws + WS_WT2);
  float*  wot    = (float*)(ws + WS_WOT);
  float*  params = (float*)(ws + WS_PARAMS);
  float*  xf     = (float*)(ws + WS_XF);

  if (blk < 20) {                       // weight fragments
    const int L = blk >> 2, w = blk & 3;
    const void* src = (L == 0) ? W20 : (L == 1) ? W11 : (L == 2) ? W21
                    : (L == 3) ? W12 : W22;
#pragma unroll
    for (int uu = 0; uu < 2; ++uu) {
      const int u = tid + uu * 256;     // 512 units: (mt,kk,lane)
      const int mt = u >> 8, kk = (u >> 6) & 3, lane = u & 63;
      const int ln = lane & 15, quad = lane >> 4;
      const int cp = w * 32 + mt * 16 + ln;
      ushort* dst = wt2 + ((((L * 4 + w) * 2 + mt) * 4 + kk) * 64 + lane) * 8;
      for (int t = 0; t < 8; ++t) {
        const int k = kk * 32 + quad * 8 + t;
        union { _Float16 h; ushort us; } cv;
        cv.h = (_Float16)dload(src, k * 128 + cp, isf32);
        dst[t] = cv.us;
      }
    }
  } else if (blk == 20) {               // Wo^T fp32
    for (int idx = tid; idx < 16384; idx += 256) {
      const int o = idx >> 7, k = idx & 127;
      wot[o * 128 + k] = dload(Wo, k * 128 + o, isf32);
    }
  } else {                              // params + x + flag
    if (tid < 128) {
      const void* vecs[8] = {w10, b10, b20, b11, b21, b12, b22, bo};
      for (int v = 0; v < 8; ++v) params[v * 128 + tid] = dload(vecs[v], tid, isf32);
    }
    for (int i = tid; i < 2048; i += 256) xf[i] = dload(x, i, isf32);
    if (tid == 0) *(int*)(ws + WS_FLAG) = isf32;
  }
}

// ---- streamed weight-fragment load (L2/L1-hot) ----------------------------
__device__ __forceinline__ void loadW(half8 (&aw)[2][4],
                                      const ushort* __restrict__ wt2o,
                                      int L, int w, int lane)
{
#pragma unroll
  for (int mt = 0; mt < 2; ++mt)
#pragma unroll
    for (int kk = 0; kk < 4; ++kk)
      aw[mt][kk] = *(const half8*)(const void*)
          (wt2o + ((((L * 4 + w) * 2 + mt) * 4 + kk) * 64 + lane) * 8);
}

// ---- swapped-form GEMM layer (CJ j-rows) ----------------------------------
// D[c'][j] = sum_c W[c][c'] * act[j][c]; A = W^T (regs), B = act (LDS b128).
// C/D: lane l reg r -> c' = w*32+mt*16+quad*4+r, j = nt*16+ln -> b64 store.
// Bias read from LDS (sbiasL = &sbias[L][0]) into acc-init.
template<int ACT>
__device__ __forceinline__ void layerS(
    const ushort* sIn, ushort* sOut, const half8 (&aw)[2][4],
    const float* sbiasL, int ln, int quad, int w)
{
  floatx4 bb0 = *(const floatx4*)(const void*)(sbiasL + w * 32 + quad * 4);
  floatx4 bb1 = *(const floatx4*)(const void*)(sbiasL + w * 32 + 16 + quad * 4);
#pragma unroll
  for (int nt = 0; nt < CJ / 16; ++nt) {
    half8 bF[4];
    const ushort* rp = sIn + (nt * 16 + ln) * LDP + quad * 8;
#pragma unroll
    for (int kk = 0; kk < 4; ++kk)
      bF[kk] = *(const half8*)(const void*)(rp + kk * 32);
#pragma unroll
    for (int mt = 0; mt < 2; ++mt) {
      floatx4 acc = mt ? bb1 : bb0;   // bias pre-loaded into accumulator
#pragma unroll
      for (int kk = 0; kk < 4; ++kk)
        acc = __builtin_amdgcn_mfma_f32_16x16x32_f16(aw[mt][kk], bF[kk], acc, 0, 0, 0);
      half4 hv;
#pragma unroll
      for (int r = 0; r < 4; ++r) {
        float v = acc[r];
        if (ACT) v = silu_f(v);
        hv[r] = (_Float16)v;
      }
      *(half4*)(void*)(sOut + (nt * 16 + ln) * LDP + w * 32 + mt * 16 + quad * 4) = hv;
    }
  }
}

// last layer (W22): accumulate per-lane partial column sums, no store
__device__ __forceinline__ void layerR(
    const ushort* sIn, const half8 (&aw)[2][4], floatx4 (&psum)[2],
    int ln, int quad)
{
#pragma unroll
  for (int nt = 0; nt < CJ / 16; ++nt) {
    half8 bF[4];
    const ushort* rp = sIn + (nt * 16 + ln) * LDP + quad * 8;
#pragma unroll
    for (int kk = 0; kk < 4; ++kk)
      bF[kk] = *(const half8*)(const void*)(rp + kk * 32);
#pragma unroll
    for (int mt = 0; mt < 2; ++mt) {
      floatx4 acc = {0.f, 0.f, 0.f, 0.f};
#pragma unroll
      for (int kk = 0; kk < 4; ++kk)
        acc = __builtin_amdgcn_mfma_f32_16x16x32_f16(aw[mt][kk], bF[kk], acc, 0, 0, 0);
      psum[mt] += acc;
    }
  }
}

// layer 0: a0[j][c] = silu(d_j*w10[c]+b10[c]); thread -> row tid>>2, 32-col
// quarter (tid&3)*32. Each thread computes its own row distance.
__device__ __forceinline__ void layer0_store(
    ushort* dstT, const float* __restrict__ xf, const float* sw10,
    const float* sb10, float xi0, float xi1, int bbase, int chunk, int tid)
{
  const int row = tid >> 2, c0 = (tid & 3) * 32;
  const int j = chunk * CJ + row;
  const float dx = xi0 - xf[(bbase + j) * 2 + 0];
  const float dy = xi1 - xf[(bbase + j) * 2 + 1];
  const float d = sqrtf(dx * dx + dy * dy);
  ushort* dst = dstT + row * LDP + c0;
#pragma unroll
  for (int c = 0; c < 32; c += 4) {
    const floatx4 w4 = *(const floatx4*)(const void*)(sw10 + c0 + c);
    const floatx4 b4 = *(const floatx4*)(const void*)(sb10 + c0 + c);
    half4 hv;
#pragma unroll
    for (int q = 0; q < 4; ++q)
      hv[q] = (_Float16)silu_f(d * w4[q] + b4[q]);
    *(half4*)(void*)(dst + c) = hv;
  }
}

// ---- kernel 2: fused encoder ----------------------------------------------
__global__ __launch_bounds__(256, 4) void fused5(
    const char* __restrict__ ws, void* __restrict__ out)
{
  __shared__ __align__(16) ushort sA[CJ * LDP];
  __shared__ __align__(16) ushort sB[CJ * LDP];
  __shared__ __align__(16) float sw10[128];
  __shared__ __align__(16) float sb10[128];
  __shared__ __align__(16) float sbias[4][128];   // b20,b11,b21,b12
  __shared__ __align__(16) float colsum[128];

  const int tid  = threadIdx.x;
  const int w    = tid >> 6;       // wave 0..3 owns channels 32w..32w+31
  const int lane = tid & 63;
  const int ln   = lane & 15;
  const int quad = lane >> 4;

  const int b = blockIdx.x >> 9;
  const int i = blockIdx.x & 511;
  const int bbase = b * 512;

  const int isf32      = *(const int*)(ws + WS_FLAG);
  const ushort* wt2    = (const ushort*)(ws + WS_WT2);
  const float*  wot    = (const float*)(ws + WS_WOT);
  const float*  params = (const float*)(ws + WS_PARAMS);
  const float*  xf     = (const float*)(ws + WS_XF);

  if (tid < 128) {
    sw10[tid] = params[0 * 128 + tid];
    sb10[tid] = params[1 * 128 + tid];
#pragma unroll
    for (int L = 0; L < 4; ++L)
      sbias[L][tid] = params[(2 + L) * 128 + tid];
  }
  const float xi0 = xf[(bbase + i) * 2 + 0];
  const float xi1 = xf[(bbase + i) * 2 + 1];
  __syncthreads();   // sw10/sb10/sbias ready

  floatx4 psum[2] = {{0.f,0.f,0.f,0.f},{0.f,0.f,0.f,0.f}};
  half8 aw[2][4];

  layer0_store(sA, xf, sw10, sb10, xi0, xi1, bbase, 0, tid);

  for (int chunk = 0; chunk < NCHUNK; ++chunk) {
    // opaque zero: keeps weight loads inside the chunk loop (anti-LICM).
    int zero = 0;
    asm volatile("" : "+v"(zero));
    const ushort* wt2o = wt2 + zero;

    ushort* Ta = (chunk & 1) ? sB : sA;   // a0 tile for this chunk
    ushort* Tb = (chunk & 1) ? sA : sB;

    loadW(aw, wt2o, 0, w, lane);
    __syncthreads();                                    // a0 ready
    layerS<0>(Ta, Tb, aw, sbias[0], ln, quad, w);       // t0 = a0@W20+b20
    loadW(aw, wt2o, 1, w, lane);
    __syncthreads();
    layerS<1>(Tb, Ta, aw, sbias[1], ln, quad, w);       // a1 = silu(t0@W11+b11)
    loadW(aw, wt2o, 2, w, lane);
    __syncthreads();
    layerS<0>(Ta, Tb, aw, sbias[2], ln, quad, w);       // t1 = a1@W21+b21
    loadW(aw, wt2o, 3, w, lane);
    __syncthreads();
    layerS<1>(Tb, Ta, aw, sbias[3], ln, quad, w);       // a2 = silu(t1@W12+b12)
    loadW(aw, wt2o, 4, w, lane);
    __syncthreads();
    layerR(Ta, aw, psum, ln, quad);                     // colsum partials (W22)
    if (chunk < NCHUNK - 1)                             // overlap next layer-0
      layer0_store(Tb, xf, sw10, sb10, xi0, xi1, bbase, chunk + 1, tid);
  }

  // reduce psum across the 16 ln-lanes of each quad-group; c' disjoint/wave
#pragma unroll
  for (int mt = 0; mt < 2; ++mt)
#pragma unroll
    for (int r = 0; r < 4; ++r) {
      float v = psum[mt][r];
      v += __shfl_xor(v, 1); v += __shfl_xor(v, 2);
      v += __shfl_xor(v, 4); v += __shfl_xor(v, 8);
      if (ln == 0) colsum[w * 32 + mt * 16 + quad * 4 + r] = v;
    }
  __syncthreads();

  if (tid < 128)   // mean + b22 (in place; reads happen after next barrier)
    colsum[tid] = colsum[tid] * (1.0f / 512.0f) + params[6 * 128 + tid];
  __syncthreads();

  // out[b,i,o] = mean . Wo[:,o] + bo[o]
  if (tid < 128) {
    const int o = tid;
    float s = params[7 * 128 + o];
    const floatx4* wrow = (const floatx4*)(const void*)(wot + o * 128);
#pragma unroll 4
    for (int k4 = 0; k4 < 32; ++k4) {
      const floatx4 wv = wrow[k4];
      const floatx4 cv = *(const floatx4*)(const void*)(colsum + k4 * 4);
      s += cv[0] * wv[0] + cv[1] * wv[1] + cv[2] * wv[2] + cv[3] * wv[3];
    }
    const int idx = (bbase + i) * 128 + o;
    if (isf32) ((float*)out)[idx] = s;
    else       ((ushort*)out)[idx] = f2bf(s);
  }
}

// ---- fallback (ws too small): fp32-direct, gathered bf16 weights ----------
template<bool ACT>
__device__ __forceinline__ void gemm_tile_g(
    const ushort* sIn, ushort* sOut, const float* __restrict__ W,
    const float* bias, int wave, int ln, int quad)
{
  typedef __attribute__((ext_vector_type(8))) short short8;
  const int row0 = wave * 32;
  short8 aF[2][4];
#pragma unroll
  for (int mt = 0; mt < 2; ++mt)
#pragma unroll
    for (int kk = 0; kk < 4; ++kk)
      aF[mt][kk] = *(const short8*)(const void*)(sIn + (row0 + mt * 16 + ln) * LDP + kk * 32 + quad * 8);
#pragma unroll
  for (int nt = 0; nt < 8; ++nt) {
    const int col = nt * 16 + ln;
    floatx4 acc0 = {0.f, 0.f, 0.f, 0.f};
    floatx4 acc1 = {0.f, 0.f, 0.f, 0.f};
#pragma unroll
    for (int kk = 0; kk < 4; ++kk) {
      short8 bF;
#pragma unroll
      for (int t = 0; t < 8; ++t)
        bF[t] = (short)f2bf(W[(kk * 32 + quad * 8 + t) * 128 + col]);
      acc0 = __builtin_amdgcn_mfma_f32_16x16x32_bf16(aF[0][kk], bF, acc0, 0, 0, 0);
      acc1 = __builtin_amdgcn_mfma_f32_16x16x32_bf16(aF[1][kk], bF, acc1, 0, 0, 0);
    }
    const float bv = bias[col];
#pragma unroll
    for (int r = 0; r < 4; ++r) {
      float v0 = acc0[r] + bv;
      float v1 = acc1[r] + bv;
      if (ACT) { v0 = silu_f(v0); v1 = silu_f(v1); }
      sOut[(row0 + quad * 4 + r) * LDP + col] = f2bf(v0);
      sOut[(row0 + 16 + quad * 4 + r) * LDP + col] = f2bf(v1);
    }
  }
}

__global__ __launch_bounds__(256, 2) void fused_direct(
    const float* __restrict__ x,
    const float* __restrict__ w10, const float* __restrict__ b10,
    const float* __restrict__ W20, const float* __restrict__ b20,
    const float* __restrict__ W11, const float* __restrict__ b11,
    const float* __restrict__ W21, const float* __restrict__ b21,
    const float* __restrict__ W12, const float* __restrict__ b12,
    const float* __restrict__ W22, const float* __restrict__ b22,
    const float* __restrict__ Wo,  const float* __restrict__ bo,
    float* __restrict__ out)
{
  __shared__ __align__(16) ushort sA[128 * LDP];
  __shared__ __align__(16) ushort sB[128 * LDP];
  __shared__ float sw10[128], sb10[128];
  __shared__ float sbias[5][128];
  __shared__ float colsum[128];
  __shared__ float dists[128];

  const int tid  = threadIdx.x;
  const int wave = tid >> 6;
  const int ln   = tid & 15;
  const int quad = (tid & 63) >> 4;
  const int b = blockIdx.x >> 9;
  const int i = blockIdx.x & 511;

  if (tid < 128) {
    sw10[tid] = w10[tid]; sb10[tid] = b10[tid];
    sbias[0][tid] = b20[tid]; sbias[1][tid] = b11[tid];
    sbias[2][tid] = b21[tid]; sbias[3][tid] = b12[tid];
    sbias[4][tid] = b22[tid]; colsum[tid] = 0.f;
  }
  const float xi0 = x[(b * 512 + i) * 2 + 0];
  const float xi1 = x[(b * 512 + i) * 2 + 1];
  __syncthreads();

  for (int chunk = 0; chunk < 4; ++chunk) {
    if (tid < 128) {
      const int j = chunk * 128 + tid;
      const float dx = xi0 - x[(b * 512 + j) * 2 + 0];
      const float dy = xi1 - x[(b * 512 + j) * 2 + 1];
      dists[tid] = sqrtf(dx * dx + dy * dy);
    }
    __syncthreads();
    for (int e = tid; e < 128 * 128; e += 256) {
      const int jj = e >> 7, c = e & 127;
      sA[jj * LDP + c] = f2bf(silu_f(dists[jj] * sw10[c] + sb10[c]));
    }
    __syncthreads();
    gemm_tile_g<false>(sA, sB, W20, sbias[0], wave, ln, quad);
    __syncthreads();
    gemm_tile_g<true >(sB, sA, W11, sbias[1], wave, ln, quad);
    __syncthreads();
    gemm_tile_g<false>(sA, sB, W21, sbias[2], wave, ln, quad);
    __syncthreads();
    gemm_tile_g<true >(sB, sA, W12, sbias[3], wave, ln, quad);
    __syncthreads();
    gemm_tile_g<false>(sB, sB, W22, sbias[4], wave, ln, quad);
    __syncthreads();
    if (tid < 128) {
      float s = 0.f;
      for (int jj = 0; jj < 128; ++jj) s += bf2f(sB[jj * LDP + tid]);
      atomicAdd(&colsum[tid], s);
    }
    __syncthreads();
  }

  if (tid < 128) {
    const int o = tid;
    float s = bo[o];
    for (int k = 0; k < 128; ++k) s += (colsum[k] * (1.0f / 512.0f)) * Wo[k * 128 + o];
    out[(b * 512 + i) * 128 + o] = s;
  }
}

extern "C" void kernel_launch(void* const* d_in, const int* in_sizes, int n_in,
                              void* d_out, int out_size, void* d_ws, size_t ws_size,
                              hipStream_t stream) {
  (void)in_sizes; (void)n_in; (void)out_size;
  if (ws_size >= (size_t)WS_NEED) {
    prep_kernel<<<22, 256, 0, stream>>>(
        d_in[0], d_in[1], d_in[2], d_in[3], d_in[4], d_in[5], d_in[6],
        d_in[7], d_in[8], d_in[9], d_in[10], d_in[11], d_in[12], d_in[13],
        d_in[14], (char*)d_ws);
    fused5<<<1024, 256, 0, stream>>>((const char*)d_ws, d_out);
  } else {
    fused_direct<<<1024, 256, 0, stream>>>(
        (const float*)d_in[0], (const float*)d_in[1], (const float*)d_in[2],
        (const float*)d_in[3], (const float*)d_in[4], (const float*)d_in[5],
        (const float*)d_in[6], (const float*)d_in[7], (const float*)d_in[8],
        (const float*)d_in[9], (const float*)d_in[10], (const float*)d_in[11],
        (const float*)d_in[12], (const float*)d_in[13], (const float*)d_in[14],
        (float*)d_out);
  }
}